// Round 2
// baseline (137.881 us; speedup 1.0000x reference)
//
#include <hip/hip_runtime.h>

#define POOL_H 7
#define POOL_W 7
#define CHANS  256

typedef float v4f __attribute__((ext_vector_type(4)));

// ---------------------------------------------------------------------------
// Kernel 1: per-ROI pyramid level + STABLE counting sort by level (matches
// jnp.argsort(lvl, stable=True)). Single block, 1024 threads (N=1000).
// Keeps the precise logf path: hardware v_log_f32 risks flipping a ROI at a
// level boundary (O(1) output error); this kernel is ~3 us, not worth it.
// ---------------------------------------------------------------------------
__global__ void __launch_bounds__(1024) level_sort_kernel(
    const float* __restrict__ rois, int N,
    int* __restrict__ sorted_lvl, float4* __restrict__ sorted_box)
{
    __shared__ int hist[16][4];   // [wave][level]

    const int tid  = threadIdx.x;
    const int wave = tid >> 6;
    const int lane = tid & 63;

    int lvl = -1;
    float y1 = 0.f, x1 = 0.f, y2 = 0.f, x2 = 0.f;
    if (tid < N) {
        y1 = rois[tid * 4 + 0];
        x1 = rois[tid * 4 + 1];
        y2 = rois[tid * 4 + 2];
        x2 = rois[tid * 4 + 3];
        float h = y2 - y1;
        float w = x2 - x1;
        // lvl = round(log(sqrt(h*w))/log(2) - 5), clip [0,3]; rintf = RNE.
        float l = logf(sqrtf(h * w)) / logf(2.0f);
        int li = (int)rintf(l - 5.0f);
        lvl = li < 0 ? 0 : (li > 3 ? 3 : li);
    }

    unsigned long long mask[4];
    #pragma unroll
    for (int l = 0; l < 4; ++l) mask[l] = __ballot(lvl == l);
    if (lane == 0) {
        #pragma unroll
        for (int l = 0; l < 4; ++l) hist[wave][l] = __popcll(mask[l]);
    }
    __syncthreads();

    if (lvl >= 0) {
        int pos = __popcll(mask[lvl] & ((1ull << lane) - 1ull));
        for (int w2 = 0; w2 < wave; ++w2) pos += hist[w2][lvl];
        for (int l = 0; l < lvl; ++l)
            #pragma unroll
            for (int w2 = 0; w2 < 16; ++w2) pos += hist[w2][l];

        sorted_lvl[pos] = lvl;
        const float inv = 1.0f / 1024.0f;   // exact (power of two)
        sorted_box[pos] = make_float4(y1 * inv, x1 * inv, y2 * inv, x2 * inv);
    }
}

// ---------------------------------------------------------------------------
// Kernel 2: ONE BLOCK PER ROI. 448 threads = 7 waves; wave = pool row py,
// px loop unrolled inside the wave. All 49 positions of an ROI execute on a
// single CU, temporally adjacent:
//   - px -> px+1 shares 2 of 4 bilinear corner rows  -> L1 hit
//   - row py's y1-row == row (py+1)'s y0-row         -> L1/L2 hit (same CU)
// so the ~8x8-texel ROI window (~100 KB) is fetched ~once from L3/HBM instead
// of once per position-block (old grid spread an ROI's blocks 1000 ids apart,
// blowing the 4 MiB per-XCD L2: ~23 MB in-flight working set).
// Lane l handles channels [4l,4l+4) as float4: 16B/lane coalesced.
// Output stores are NONTEMPORAL so the 50 MB streaming write doesn't evict
// the feature window from L2.
// ---------------------------------------------------------------------------
__global__ void __launch_bounds__(448) roi_align_kernel(
    const float* __restrict__ f0, const float* __restrict__ f1,
    const float* __restrict__ f2, const float* __restrict__ f3,
    const int* __restrict__ sorted_lvl, const float4* __restrict__ sorted_box,
    float* __restrict__ out)
{
    const int n    = blockIdx.x;
    const int py   = threadIdx.x >> 6;   // 0..6  (wave index = pool row)
    const int lane = threadIdx.x & 63;   // channel group

    const int lvl = sorted_lvl[n];
    const float4 box = sorted_box[n];

    const float* feat;
    int HW;
    switch (lvl) {
        case 0:  feat = f0; HW = 256; break;
        case 1:  feat = f1; HW = 128; break;
        case 2:  feat = f2; HW = 64;  break;
        default: feat = f3; HW = 32;  break;
    }
    const float Hm1 = (float)(HW - 1);

    // iy = y1*(H-1) + py * (y2-y1)*(H-1)/6   (same for x, W=H)
    const float sy = (box.z - box.x) * Hm1 * (1.0f / 6.0f);
    const float sx = (box.w - box.y) * Hm1 * (1.0f / 6.0f);

    const float iy  = box.x * Hm1 + (float)py * sy;
    const float y0f = floorf(iy);
    const float ly  = iy - y0f;
    int y0  = (int)y0f;
    int y1i = y0 + 1;
    y0  = min(max(y0,  0), HW - 1);
    y1i = min(max(y1i, 0), HW - 1);
    const bool vy = (iy >= 0.0f) & (iy <= Hm1);

    // Per-wave row bases: all px iterations read from these two feature rows.
    const float4* row0 = (const float4*)(feat + (size_t)(y0  * HW) * CHANS) + lane;
    const float4* row1 = (const float4*)(feat + (size_t)(y1i * HW) * CHANS) + lane;

    float4* outp = (float4*)(out + (size_t)n * (POOL_H * POOL_W * CHANS))
                   + py * (POOL_W * 64) + lane;

    const float ix_base = box.y * Hm1;

    #pragma unroll
    for (int px = 0; px < POOL_W; ++px) {
        const float ix  = ix_base + (float)px * sx;
        const float x0f = floorf(ix);
        const float lx  = ix - x0f;
        int x0  = (int)x0f;
        int x1i = x0 + 1;
        x0  = min(max(x0,  0), HW - 1);
        x1i = min(max(x1i, 0), HW - 1);
        const bool valid = vy & (ix >= 0.0f) & (ix <= Hm1);

        const float4 f00 = row0[(size_t)x0  * 64];
        const float4 f01 = row0[(size_t)x1i * 64];
        const float4 f10 = row1[(size_t)x0  * 64];
        const float4 f11 = row1[(size_t)x1i * 64];

        float4 val;
        {
            float tx, bx;
            tx = f00.x + (f01.x - f00.x) * lx;
            bx = f10.x + (f11.x - f10.x) * lx;
            val.x = tx + (bx - tx) * ly;
            tx = f00.y + (f01.y - f00.y) * lx;
            bx = f10.y + (f11.y - f10.y) * lx;
            val.y = tx + (bx - tx) * ly;
            tx = f00.z + (f01.z - f00.z) * lx;
            bx = f10.z + (f11.z - f10.z) * lx;
            val.z = tx + (bx - tx) * ly;
            tx = f00.w + (f01.w - f00.w) * lx;
            bx = f10.w + (f11.w - f10.w) * lx;
            val.w = tx + (bx - tx) * ly;
        }
        if (!valid) { val.x = 0.f; val.y = 0.f; val.z = 0.f; val.w = 0.f; }

        // Streaming store: don't let the 50 MB output evict the feature
        // window from L2. ext_vector_type cast: HIP's float4 class isn't
        // accepted by __builtin_nontemporal_store.
        v4f vv;
        vv.x = val.x; vv.y = val.y; vv.z = val.z; vv.w = val.w;
        __builtin_nontemporal_store(vv, (v4f*)&outp[px * 64]);
    }
}

extern "C" void kernel_launch(void* const* d_in, const int* in_sizes, int n_in,
                              void* d_out, int out_size, void* d_ws, size_t ws_size,
                              hipStream_t stream) {
    const float* f0   = (const float*)d_in[0];
    const float* f1   = (const float*)d_in[1];
    const float* f2   = (const float*)d_in[2];
    const float* f3   = (const float*)d_in[3];
    const float* rois = (const float*)d_in[4];
    const int N = in_sizes[4] / 4;

    int*    sorted_lvl = (int*)d_ws;
    float4* sorted_box = (float4*)((char*)d_ws + 4096);
    float*  out        = (float*)d_out;

    hipLaunchKernelGGL(level_sort_kernel, dim3(1), dim3(1024), 0, stream,
                       rois, N, sorted_lvl, sorted_box);

    hipLaunchKernelGGL(roi_align_kernel, dim3(N), dim3(448), 0, stream,
                       f0, f1, f2, f3, sorted_lvl, sorted_box, out);
}